// Round 1
// baseline (137.583 us; speedup 1.0000x reference)
//
#include <hip/hip_runtime.h>
#include <hip/hip_bf16.h>

#define BB 4096
#define DD 256
#define CC 5994
#define CPAD 6016
#define NCHUNK 376        // CPAD/16
#define SPLIT 8
#define CHUNKS_PER 47     // NCHUNK/SPLIT
#define SCALEF 30.0f
#define COSM 0.9800665778412416f   // cos(0.2)
#define SINM 0.19866933079506122f  // sin(0.2)

typedef __attribute__((ext_vector_type(8))) short bf16x8;
typedef __attribute__((ext_vector_type(4))) float f32x4;

__device__ __forceinline__ unsigned short f2bf(float f) {
  union { float f; unsigned u; } v; v.f = f;
  unsigned r = v.u + 0x7fffu + ((v.u >> 16) & 1u);
  return (unsigned short)(r >> 16);
}

// ---------------- kernel 1: normalize rows of x -> bf16 xn[B][D] ----------------
__global__ void k_xnorm(const float* __restrict__ x, unsigned short* __restrict__ xn) {
  int row = blockIdx.x;
  int l = threadIdx.x;  // 0..63
  float4 v = reinterpret_cast<const float4*>(x + (size_t)row * DD)[l];
  float ss = v.x * v.x + v.y * v.y + v.z * v.z + v.w * v.w;
#pragma unroll
  for (int m = 32; m >= 1; m >>= 1) ss += __shfl_xor(ss, m, 64);
  float inv = 1.0f / fmaxf(sqrtf(ss), 1e-12f);
  ushort4 o;
  o.x = f2bf(v.x * inv); o.y = f2bf(v.y * inv);
  o.z = f2bf(v.z * inv); o.w = f2bf(v.w * inv);
  reinterpret_cast<ushort4*>(xn + (size_t)row * DD)[l] = o;
}

// ------- kernel 2: normalize cols of W, transpose -> bf16 wnT[CPAD][D] (pad=0) -------
__global__ void k_wnorm(const float* __restrict__ W, unsigned short* __restrict__ wnT) {
  __shared__ float lds[64 * 257];
  __shared__ float ssp[256];
  __shared__ float sinv[64];
  int t = threadIdx.x;
  int t63 = t & 63, tg = t >> 6;
  int c0 = blockIdx.x * 64;
  int c = c0 + t63;
  float ss = 0.0f;
  for (int d = tg * 64; d < tg * 64 + 64; ++d) {
    float v = (c < CC) ? W[(size_t)d * CC + c] : 0.0f;  // coalesced across t63
    lds[t63 * 257 + d] = v;
    ss += v * v;
  }
  ssp[t] = ss;
  __syncthreads();
  if (t < 64) {
    float tot = ssp[t] + ssp[t + 64] + ssp[t + 128] + ssp[t + 192];
    sinv[t] = (c0 + t < CC) ? 1.0f / fmaxf(sqrtf(tot), 1e-12f) : 0.0f;
  }
  __syncthreads();
  for (int r = tg * 16; r < tg * 16 + 16; ++r) {
    float inv = sinv[r];
    ushort4 o;
    o.x = f2bf(lds[r * 257 + t63 * 4 + 0] * inv);
    o.y = f2bf(lds[r * 257 + t63 * 4 + 1] * inv);
    o.z = f2bf(lds[r * 257 + t63 * 4 + 2] * inv);
    o.w = f2bf(lds[r * 257 + t63 * 4 + 3] * inv);
    reinterpret_cast<ushort4*>(wnT + (size_t)(c0 + r) * DD)[t63] = o;
  }
}

// ---- kernel 3: fused MFMA GEMM + online softmax stats per (16-row tile, col part) ----
__launch_bounds__(256)
__global__ void k_main(const unsigned short* __restrict__ xn,
                       const unsigned short* __restrict__ wnT,
                       const int* __restrict__ label,
                       float* __restrict__ mp, float* __restrict__ sp,
                       float* __restrict__ av, int* __restrict__ ai,
                       float* __restrict__ tp) {
  int wave = blockIdx.x * 4 + (threadIdx.x >> 6);
  int l = threadIdx.x & 63;
  int tile = wave >> 3;   // 0..255 -> 16-row tile
  int part = wave & 7;    // column partition
  int r0 = tile * 16;
  int lg = l >> 4;        // k-group 0..3
  int lr = l & 15;

  // A fragments: lane holds A[row=lr][k = ks*32 + lg*8 .. +8], row-tile fixed for this wave
  bf16x8 a[8];
  const unsigned short* ap = xn + (size_t)(r0 + lr) * DD + lg * 8;
#pragma unroll
  for (int ks = 0; ks < 8; ++ks) a[ks] = *reinterpret_cast<const bf16x8*>(ap + ks * 32);

  // labels for this lane's 4 output rows (row = r0 + lg*4 + j)
  int lab[4];
#pragma unroll
  for (int j = 0; j < 4; ++j) lab[j] = label[r0 + lg * 4 + j];

  float m[4], s[4], amv[4], tg[4]; int ami[4];
#pragma unroll
  for (int j = 0; j < 4; ++j) {
    m[j] = -1e30f; s[j] = 0.f; amv[j] = -1e30f; tg[j] = -1e30f; ami[j] = 0x7fffffff;
  }

  for (int nc = part * CHUNKS_PER; nc < (part + 1) * CHUNKS_PER; ++nc) {
    int col = nc * 16 + lr;
    const unsigned short* bp = wnT + (size_t)col * DD + lg * 8;
    bf16x8 b[8];
#pragma unroll
    for (int ks = 0; ks < 8; ++ks) b[ks] = *reinterpret_cast<const bf16x8*>(bp + ks * 32);
    f32x4 acc = {0.f, 0.f, 0.f, 0.f};
#pragma unroll
    for (int ks = 0; ks < 8; ++ks)
      acc = __builtin_amdgcn_mfma_f32_16x16x32_bf16(a[ks], b[ks], acc, 0, 0, 0);

    if (col < CC) {
#pragma unroll
      for (int j = 0; j < 4; ++j) {  // D[row = r0+lg*4+j][col], col = lane's column
        float v = acc[j];
        v = fminf(fmaxf(v, -1.0f + 1e-7f), 1.0f + 1e-7f);
        float lgt;
        if (col == lab[j]) {
          float sn = sqrtf(fmaxf(1.0f - v * v, 0.0f));
          lgt = SCALEF * (v * COSM - sn * SINM);
          tg[j] = lgt;
        } else {
          lgt = SCALEF * v;
        }
        float nm = fmaxf(m[j], lgt);
        s[j] = s[j] * __expf(m[j] - nm) + __expf(lgt - nm);
        m[j] = nm;
        if (lgt > amv[j]) { amv[j] = lgt; ami[j] = col; }
      }
    }
  }

  // reduce across the 16 lanes sharing each output row (xor masks stay within 16-group)
#pragma unroll
  for (int j = 0; j < 4; ++j) {
#pragma unroll
    for (int mk = 1; mk < 16; mk <<= 1) {
      float om = __shfl_xor(m[j], mk, 64);
      float os = __shfl_xor(s[j], mk, 64);
      float nm = fmaxf(m[j], om);
      s[j] = s[j] * __expf(m[j] - nm) + os * __expf(om - nm);
      m[j] = nm;
      float oav = __shfl_xor(amv[j], mk, 64);
      int   oai = __shfl_xor(ami[j], mk, 64);
      if (oav > amv[j] || (oav == amv[j] && oai < ami[j])) { amv[j] = oav; ami[j] = oai; }
      float ot = __shfl_xor(tg[j], mk, 64);
      tg[j] = fmaxf(tg[j], ot);
    }
    if (lr == 0) {
      int row = r0 + lg * 4 + j;
      int idx = row * SPLIT + part;
      mp[idx] = m[j]; sp[idx] = s[j]; av[idx] = amv[j]; ai[idx] = ami[j]; tp[idx] = tg[j];
    }
  }
}

// ---------------- kernel 4: combine partials per row, reduce loss/acc ----------------
__global__ void k_combine(const float* __restrict__ mp, const float* __restrict__ sp,
                          const float* __restrict__ av, const int* __restrict__ ai,
                          const float* __restrict__ tp, const int* __restrict__ label,
                          float* __restrict__ accum) {
  int row = blockIdx.x * 64 + threadIdx.x;
  float m = -1e30f, s = 0.f, amv = -1e30f, tg = -1e30f; int ami = 0x7fffffff;
#pragma unroll
  for (int p = 0; p < SPLIT; ++p) {
    int idx = row * SPLIT + p;
    float om = mp[idx], os = sp[idx];
    float nm = fmaxf(m, om);
    s = s * __expf(m - nm) + os * __expf(om - nm);
    m = nm;
    float oav = av[idx]; int oai = ai[idx];
    if (oav > amv || (oav == amv && oai < ami)) { amv = oav; ami = oai; }
    tg = fmaxf(tg, tp[idx]);
  }
  float loss = (m + logf(s)) - tg;
  float corr = (ami == label[row]) ? 1.0f : 0.0f;
#pragma unroll
  for (int k = 32; k >= 1; k >>= 1) {
    loss += __shfl_xor(loss, k, 64);
    corr += __shfl_xor(corr, k, 64);
  }
  if (threadIdx.x == 0) {
    atomicAdd(accum + 0, loss);
    atomicAdd(accum + 1, corr);
  }
}

// ---------------- kernel 5: finalize ----------------
__global__ void k_final(const float* __restrict__ accum, float* __restrict__ out) {
  out[0] = accum[0] / (float)BB;
  out[1] = accum[1] * (100.0f / (float)BB);
}

extern "C" void kernel_launch(void* const* d_in, const int* in_sizes, int n_in,
                              void* d_out, int out_size, void* d_ws, size_t ws_size,
                              hipStream_t stream) {
  const float* x = (const float*)d_in[0];
  const float* W = (const float*)d_in[1];
  const int* label = (const int*)d_in[2];
  float* out = (float*)d_out;

  char* ws = (char*)d_ws;
  // layout (bytes):
  unsigned short* wnT = (unsigned short*)(ws);                 // CPAD*DD*2 = 3,080,192
  unsigned short* xn  = (unsigned short*)(ws + 3080192);       // BB*DD*2   = 2,097,152
  size_t po = 3080192 + 2097152;                               // 5,177,344
  float* mp = (float*)(ws + po + 0 * 131072);
  float* sp = (float*)(ws + po + 1 * 131072);
  float* av = (float*)(ws + po + 2 * 131072);
  float* tp = (float*)(ws + po + 3 * 131072);
  int*   ai = (int*)  (ws + po + 4 * 131072);
  float* accum = (float*)(ws + po + 5 * 131072);

  hipMemsetAsync(accum, 0, 8, stream);
  k_xnorm<<<BB, 64, 0, stream>>>(x, xn);
  k_wnorm<<<CPAD / 64, 256, 0, stream>>>(W, wnT);
  k_main<<<512, 256, 0, stream>>>(xn, wnT, label, mp, sp, av, ai, tp);
  k_combine<<<BB / 64, 64, 0, stream>>>(mp, sp, av, ai, tp, label, accum);
  k_final<<<1, 1, 0, stream>>>(accum, out);
}

// Round 2
// 69.425 us; speedup vs baseline: 1.9817x; 1.9817x over previous
//
#include <hip/hip_runtime.h>
#include <hip/hip_bf16.h>

#define BB 4096
#define DD 256
#define CC 5994
#define CPAD 6016
#define NCHUNK 376        // CPAD/16
#define SPLIT 8
#define NSUB 47           // chunks per column-part
#define SCALEF 30.0f
#define COSM 0.9800665778412416f   // cos(0.2)
#define SINM 0.19866933079506122f  // sin(0.2)

typedef __attribute__((ext_vector_type(8))) short bf16x8;
typedef __attribute__((ext_vector_type(4))) float f32x4;

__device__ __forceinline__ unsigned short f2bf(float f) {
  union { float f; unsigned u; } v; v.f = f;
  unsigned r = v.u + 0x7fffu + ((v.u >> 16) & 1u);
  return (unsigned short)(r >> 16);
}

// ---------------- kernel 1: normalize rows of x -> bf16 xn[B][D] ----------------
__global__ void k_xnorm(const float* __restrict__ x, unsigned short* __restrict__ xn) {
  int tgi = threadIdx.x >> 6, l = threadIdx.x & 63;
  int row = blockIdx.x * 4 + tgi;
  float4 v = reinterpret_cast<const float4*>(x + (size_t)row * DD)[l];
  float ss = v.x * v.x + v.y * v.y + v.z * v.z + v.w * v.w;
#pragma unroll
  for (int m = 32; m >= 1; m >>= 1) ss += __shfl_xor(ss, m, 64);
  float inv = 1.0f / fmaxf(sqrtf(ss), 1e-12f);
  ushort4 o;
  o.x = f2bf(v.x * inv); o.y = f2bf(v.y * inv);
  o.z = f2bf(v.z * inv); o.w = f2bf(v.w * inv);
  reinterpret_cast<ushort4*>(xn + (size_t)row * DD)[l] = o;
}

// ------- kernel 2: normalize cols of W -> bf16, chunk-swizzled layout -------
// wnT elem offset = chunk*4096 + ks*512 + lg*128 + lr*8 + h
//   where col = chunk*16 + lr, k = ks*32 + lg*8 + h   (pad cols = 0)
__global__ void k_wnorm(const float* __restrict__ W, unsigned short* __restrict__ wnT) {
  __shared__ float lds[64 * 257];
  __shared__ float ssp[256];
  __shared__ float sinv[64];
  int t = threadIdx.x;
  int t63 = t & 63, tg = t >> 6;
  int c0 = blockIdx.x * 64;
  int c = c0 + t63;
  float ss = 0.0f;
  for (int d = tg * 64; d < tg * 64 + 64; ++d) {
    float v = (c < CC) ? W[(size_t)d * CC + c] : 0.0f;  // coalesced across t63
    lds[t63 * 257 + d] = v;
    ss += v * v;
  }
  ssp[t] = ss;
  __syncthreads();
  if (t < 64) {
    float tot = ssp[t] + ssp[t + 64] + ssp[t + 128] + ssp[t + 192];
    sinv[t] = (c0 + t < CC) ? 1.0f / fmaxf(sqrtf(tot), 1e-12f) : 0.0f;
  }
  __syncthreads();
  // thread t63 handles k0 = t63*4 (one ushort4 per col); tg handles 16 cols
  int ks = t63 >> 3, lg2 = (t63 >> 1) & 3, h0 = (t63 & 1) * 4;
  int k0 = t63 * 4;
  for (int r = tg * 16; r < tg * 16 + 16; ++r) {
    float inv = sinv[r];
    int chunk = blockIdx.x * 4 + (r >> 4);
    int lr = r & 15;
    ushort4 o;
    o.x = f2bf(lds[r * 257 + k0 + 0] * inv);
    o.y = f2bf(lds[r * 257 + k0 + 1] * inv);
    o.z = f2bf(lds[r * 257 + k0 + 2] * inv);
    o.w = f2bf(lds[r * 257 + k0 + 3] * inv);
    *reinterpret_cast<ushort4*>(wnT + (size_t)chunk * 4096 + ks * 512 + lg2 * 128 + lr * 8 + h0) = o;
  }
}

// ---- kernel 3: fused MFMA GEMM + softmax stats. Block = 64 rows x 1/8 cols ----
__launch_bounds__(256, 2)
__global__ void k_main(const unsigned short* __restrict__ xn,
                       const unsigned short* __restrict__ wnTs,
                       const int* __restrict__ label,
                       float* __restrict__ sp, float* __restrict__ av,
                       int* __restrict__ ai, float* __restrict__ tp) {
  __shared__ unsigned short ldsB[2][4096];  // 2 x 8KB double buffer
  int t = threadIdx.x;
  int w = t >> 6, l = t & 63;
  int lg = l >> 4, lr = l & 15;
  int blockrow = blockIdx.x >> 3;   // 0..63
  int part = blockIdx.x & 7;        // 0..7
  int r0w = blockrow * 64 + w * 16; // this wave's 16-row tile
  int nc0 = part * NSUB;

  // A fragments: lane holds A[row=r0w+lr][k = ks*32 + lg*8 .. +8]
  bf16x8 a[8];
  const unsigned short* ap = xn + (size_t)(r0w + lr) * DD + lg * 8;
#pragma unroll
  for (int ks = 0; ks < 8; ++ks) a[ks] = *reinterpret_cast<const bf16x8*>(ap + ks * 32);

  int lab[4];
#pragma unroll
  for (int j = 0; j < 4; ++j) lab[j] = label[r0w + lg * 4 + j];

  float s[4], amv[4], tg[4]; int ami[4];
#pragma unroll
  for (int j = 0; j < 4; ++j) { s[j] = 0.f; amv[j] = -1e30f; tg[j] = -1e30f; ami[j] = 0x7fffffff; }

  // prologue: stage chunk nc0 into buffer 0
  {
    const uint4* g = reinterpret_cast<const uint4*>(wnTs + (size_t)nc0 * 4096);
    uint4 v0 = g[t], v1 = g[t + 256];
    uint4* d = reinterpret_cast<uint4*>(&ldsB[0][0]);
    d[t] = v0; d[t + 256] = v1;
  }
  __syncthreads();

  for (int it = 0; it < NSUB; ++it) {
    int nc = nc0 + it;
    uint4 nx0, nx1;
    bool pf = (it + 1 < NSUB);
    if (pf) {  // issue next-chunk loads early; latency hides under MFMA+epilogue
      const uint4* g = reinterpret_cast<const uint4*>(wnTs + (size_t)(nc + 1) * 4096);
      nx0 = g[t]; nx1 = g[t + 256];
    }
    // B fragments from LDS: lane l reads contiguous 16B at ks*1024 + l*16 (conflict-free)
    const unsigned short* lb = ldsB[it & 1];
    bf16x8 b[8];
#pragma unroll
    for (int ks = 0; ks < 8; ++ks)
      b[ks] = *reinterpret_cast<const bf16x8*>(lb + ks * 512 + l * 8);
    f32x4 acc = {0.f, 0.f, 0.f, 0.f};
#pragma unroll
    for (int ks = 0; ks < 8; ++ks)
      acc = __builtin_amdgcn_mfma_f32_16x16x32_bf16(a[ks], b[ks], acc, 0, 0, 0);

    int col = nc * 16 + lr;
    if (col < CC) {
#pragma unroll
      for (int j = 0; j < 4; ++j) {  // D[row=r0w+lg*4+j][col]
        float v = fminf(fmaxf(acc[j], -1.0f + 1e-7f), 1.0f + 1e-7f);
        float lgt = SCALEF * v;
        if (col == lab[j]) {  // rare divergent path: margin on target class
          float sn = sqrtf(fmaxf(1.0f - v * v, 0.0f));
          lgt = SCALEF * (v * COSM - sn * SINM);
          tg[j] = lgt;
        }
        s[j] += __expf(lgt - SCALEF);  // fixed max M=30: logits bounded by 30
        if (lgt > amv[j]) { amv[j] = lgt; ami[j] = col; }
      }
    }
    if (pf) {  // write-late into the other buffer, then publish
      uint4* d = reinterpret_cast<uint4*>(&ldsB[(it + 1) & 1][0]);
      d[t] = nx0; d[t + 256] = nx1;
    }
    __syncthreads();
  }

  // reduce across the 16 lanes sharing each output row
#pragma unroll
  for (int j = 0; j < 4; ++j) {
#pragma unroll
    for (int mk = 1; mk < 16; mk <<= 1) {
      s[j] += __shfl_xor(s[j], mk, 64);
      float oav = __shfl_xor(amv[j], mk, 64);
      int   oai = __shfl_xor(ami[j], mk, 64);
      if (oav > amv[j] || (oav == amv[j] && oai < ami[j])) { amv[j] = oav; ami[j] = oai; }
      tg[j] = fmaxf(tg[j], __shfl_xor(tg[j], mk, 64));
    }
    if (lr == 0) {
      int row = r0w + lg * 4 + j;
      int idx = row * SPLIT + part;
      sp[idx] = s[j]; av[idx] = amv[j]; ai[idx] = ami[j]; tp[idx] = tg[j];
    }
  }
}

// ---------------- kernel 4: combine partials per row, reduce loss/acc ----------------
__global__ void k_combine(const float* __restrict__ sp, const float* __restrict__ av,
                          const int* __restrict__ ai, const float* __restrict__ tp,
                          const int* __restrict__ label, float* __restrict__ accum) {
  int row = blockIdx.x * 64 + threadIdx.x;
  float s = 0.f, amv = -1e30f, tg = -1e30f; int ami = 0x7fffffff;
#pragma unroll
  for (int p = 0; p < SPLIT; ++p) {
    int idx = row * SPLIT + p;
    s += sp[idx];
    float oav = av[idx]; int oai = ai[idx];
    if (oav > amv || (oav == amv && oai < ami)) { amv = oav; ami = oai; }
    tg = fmaxf(tg, tp[idx]);
  }
  float loss = (SCALEF + logf(s)) - tg;
  float corr = (ami == label[row]) ? 1.0f : 0.0f;
#pragma unroll
  for (int k = 32; k >= 1; k >>= 1) {
    loss += __shfl_xor(loss, k, 64);
    corr += __shfl_xor(corr, k, 64);
  }
  if (threadIdx.x == 0) {
    atomicAdd(accum + 0, loss);
    atomicAdd(accum + 1, corr);
  }
}

// ---------------- kernel 5: finalize ----------------
__global__ void k_final(const float* __restrict__ accum, float* __restrict__ out) {
  out[0] = accum[0] / (float)BB;
  out[1] = accum[1] * (100.0f / (float)BB);
}

extern "C" void kernel_launch(void* const* d_in, const int* in_sizes, int n_in,
                              void* d_out, int out_size, void* d_ws, size_t ws_size,
                              hipStream_t stream) {
  const float* x = (const float*)d_in[0];
  const float* W = (const float*)d_in[1];
  const int* label = (const int*)d_in[2];
  float* out = (float*)d_out;

  char* ws = (char*)d_ws;
  unsigned short* wnT = (unsigned short*)(ws);                 // 3,080,192 B
  unsigned short* xn  = (unsigned short*)(ws + 3080192);       // 2,097,152 B
  size_t po = 5177344;
  float* sp = (float*)(ws + po + 0 * 131072);
  float* av = (float*)(ws + po + 1 * 131072);
  float* tp = (float*)(ws + po + 2 * 131072);
  int*   ai = (int*)  (ws + po + 3 * 131072);
  float* accum = (float*)(ws + po + 4 * 131072);

  hipMemsetAsync(accum, 0, 8, stream);
  k_xnorm<<<BB / 4, 256, 0, stream>>>(x, xn);
  k_wnorm<<<CPAD / 64, 256, 0, stream>>>(W, wnT);
  k_main<<<512, 256, 0, stream>>>(xn, wnT, label, sp, av, ai, tp);
  k_combine<<<BB / 64, 64, 0, stream>>>(sp, av, ai, tp, label, accum);
  k_final<<<1, 1, 0, stream>>>(accum, out);
}

// Round 3
// 43.679 us; speedup vs baseline: 3.1499x; 1.5894x over previous
//
#include <hip/hip_runtime.h>
#include <hip/hip_bf16.h>

#define BB 4096
#define DD 256
#define CC 5994
#define CPAD 6144
#define NCHUNK 384        // CPAD/16
#define PARTS 16
#define NSUB 12           // iterations of 32 cols per part (384 cols/part)
#define COSM 0.9800665778412416f   // cos(0.2)
#define SINM 0.19866933079506122f  // sin(0.2)

typedef __attribute__((ext_vector_type(8))) short bf16x8;
typedef __attribute__((ext_vector_type(4))) float f32x4;

__device__ __forceinline__ unsigned short f2bf(float f) {
  union { float f; unsigned u; } v; v.f = f;
  unsigned r = v.u + 0x7fffu + ((v.u >> 16) & 1u);
  return (unsigned short)(r >> 16);
}

// ---- kernel 1: normalize rows of x -> bf16, chunk-swizzled layout ----
// elem offset = rchunk*4096 + ks*512 + lg*128 + lr*8 + h, row=rchunk*16+lr, k=ks*32+lg*8+h
__global__ void k_xnorm(const float* __restrict__ x, unsigned short* __restrict__ xnS) {
  int tgi = threadIdx.x >> 6, l = threadIdx.x & 63;
  int row = blockIdx.x * 4 + tgi;
  float4 v = reinterpret_cast<const float4*>(x + (size_t)row * DD)[l];
  float ss = v.x * v.x + v.y * v.y + v.z * v.z + v.w * v.w;
#pragma unroll
  for (int m = 32; m >= 1; m >>= 1) ss += __shfl_xor(ss, m, 64);
  float inv = 1.0f / fmaxf(sqrtf(ss), 1e-12f);
  ushort4 o;
  o.x = f2bf(v.x * inv); o.y = f2bf(v.y * inv);
  o.z = f2bf(v.z * inv); o.w = f2bf(v.w * inv);
  // k = 4l+q -> ks = l>>3, lg = (l>>1)&3, h = 4*(l&1)+q
  int off = (row >> 4) * 4096 + (l >> 3) * 512 + ((l >> 1) & 3) * 128 + (row & 15) * 8 + (l & 1) * 4;
  *reinterpret_cast<ushort4*>(xnS + off) = o;
}

// ---- kernel 2: normalize cols of W -> bf16, chunk-swizzled layout (1 chunk/block) ----
__global__ void k_wnorm(const float* __restrict__ W, unsigned short* __restrict__ wnS) {
  __shared__ float pp[16][17];
  __shared__ float sinv[16];
  int t = threadIdx.x;
  int lr = t & 15, u = t >> 4;        // col-in-chunk, row-group
  int chunk = blockIdx.x;
  int c = chunk * 16 + lr;
  int D0 = u * 16;
  float v[16];
  float ss = 0.f;
#pragma unroll
  for (int i = 0; i < 16; ++i) {
    float xv = (c < CC) ? W[(size_t)(D0 + i) * CC + c] : 0.f;
    v[i] = xv; ss += xv * xv;
  }
  pp[u][lr] = ss;
  __syncthreads();
  if (t < 16) {
    float tot = 0.f;
#pragma unroll
    for (int g = 0; g < 16; ++g) tot += pp[g][t];
    sinv[t] = (chunk * 16 + t < CC) ? 1.0f / fmaxf(sqrtf(tot), 1e-12f) : 0.f;
  }
  __syncthreads();
  float inv = sinv[lr];
  // d = D0+i: ks = u>>1, lg = (2u&3) + (i>>3), h = i&7 -> two 16B stores
  int base = chunk * 4096 + (u >> 1) * 512 + ((2 * u) & 3) * 128 + lr * 8;
  unsigned wds[4];
#pragma unroll
  for (int q = 0; q < 4; ++q)
    wds[q] = (unsigned)f2bf(v[2 * q] * inv) | ((unsigned)f2bf(v[2 * q + 1] * inv) << 16);
  *reinterpret_cast<uint4*>(wnS + base) = make_uint4(wds[0], wds[1], wds[2], wds[3]);
#pragma unroll
  for (int q = 0; q < 4; ++q)
    wds[q] = (unsigned)f2bf(v[8 + 2 * q] * inv) | ((unsigned)f2bf(v[9 + 2 * q] * inv) << 16);
  *reinterpret_cast<uint4*>(wnS + base + 128) = make_uint4(wds[0], wds[1], wds[2], wds[3]);
}

// ---- kernel 3: fused MFMA GEMM + softmax stats. Wave = 32 rows, chunk = 32 cols ----
__launch_bounds__(256, 2)
__global__ void k_main(const unsigned short* __restrict__ xnS,
                       const unsigned short* __restrict__ wnS,
                       const int* __restrict__ label,
                       float* __restrict__ sp, float* __restrict__ vmp,
                       float* __restrict__ vtp) {
  __shared__ uint4 ldsB[2][1024];  // 2 x 16KB double buffer
  int bid = blockIdx.x;
  int sw = (bid & 7) * 64 + (bid >> 3);   // XCD-contiguous remap (512 = 8*64)
  int part = sw >> 5;                     // 0..15: column part (384 cols)
  int rowblk = sw & 31;                   // 0..31: 128-row block
  int t = threadIdx.x, w = t >> 6, l = t & 63;
  int lg = l >> 4, lr = l & 15;
  int r0 = rowblk * 128 + w * 32;         // this wave's first row (M=32)

  // A fragments (swizzled, contiguous per wave)
  bf16x8 a[2][8];
#pragma unroll
  for (int rt = 0; rt < 2; ++rt) {
    const unsigned short* ap = xnS + ((r0 >> 4) + rt) * 4096 + lg * 128 + lr * 8;
#pragma unroll
    for (int ks = 0; ks < 8; ++ks)
      a[rt][ks] = *reinterpret_cast<const bf16x8*>(ap + ks * 512);
  }
  int lab[8];
#pragma unroll
  for (int rt = 0; rt < 2; ++rt)
#pragma unroll
    for (int j = 0; j < 4; ++j) lab[rt * 4 + j] = label[r0 + rt * 16 + lg * 4 + j];

  float s[8], vm[8], vt[8];
#pragma unroll
  for (int i = 0; i < 8; ++i) { s[i] = 0.f; vm[i] = -2.f; vt[i] = -2.f; }

  const uint4* gbase = reinterpret_cast<const uint4*>(wnS + (size_t)part * NSUB * 8192);
  {  // prologue: stage iter 0
    uint4 p0 = gbase[t], p1 = gbase[t + 256], p2 = gbase[t + 512], p3 = gbase[t + 768];
    ldsB[0][t] = p0; ldsB[0][t + 256] = p1; ldsB[0][t + 512] = p2; ldsB[0][t + 768] = p3;
  }
  __syncthreads();

  for (int it = 0; it < NSUB; ++it) {
    uint4 n0, n1, n2, n3;
    bool pf = (it + 1 < NSUB);
    if (pf) {  // issue next-chunk loads early
      const uint4* g = gbase + (it + 1) * 1024;
      n0 = g[t]; n1 = g[t + 256]; n2 = g[t + 512]; n3 = g[t + 768];
    }
    const unsigned short* lb = reinterpret_cast<const unsigned short*>(&ldsB[it & 1][0]);
#pragma unroll
    for (int c2 = 0; c2 < 2; ++c2) {
      bf16x8 b[8];
#pragma unroll
      for (int ks = 0; ks < 8; ++ks)
        b[ks] = *reinterpret_cast<const bf16x8*>(lb + c2 * 4096 + ks * 512 + l * 8);
      f32x4 acc[2] = {{0.f, 0.f, 0.f, 0.f}, {0.f, 0.f, 0.f, 0.f}};
#pragma unroll
      for (int ks = 0; ks < 8; ++ks) {
        acc[0] = __builtin_amdgcn_mfma_f32_16x16x32_bf16(a[0][ks], b[ks], acc[0], 0, 0, 0);
        acc[1] = __builtin_amdgcn_mfma_f32_16x16x32_bf16(a[1][ks], b[ks], acc[1], 0, 0, 0);
      }
      int col = part * 384 + it * 32 + c2 * 16 + lr;
#pragma unroll
      for (int rt = 0; rt < 2; ++rt)
#pragma unroll
        for (int j = 0; j < 4; ++j) {
          float v = acc[rt][j];
          s[rt * 4 + j] += __expf(__builtin_fmaf(v, 30.f, -30.f));  // fixed max 30
          bool ist = (col == lab[rt * 4 + j]);
          vt[rt * 4 + j] = ist ? v : vt[rt * 4 + j];
          vm[rt * 4 + j] = fmaxf(vm[rt * 4 + j], ist ? -2.f : v);
        }
    }
    if (pf) {  // write-late into other buffer
      uint4* d = &ldsB[(it + 1) & 1][0];
      d[t] = n0; d[t + 256] = n1; d[t + 512] = n2; d[t + 768] = n3;
    }
    __syncthreads();
  }

  // reduce across the 16 lanes sharing each output row
#pragma unroll
  for (int i = 0; i < 8; ++i) {
#pragma unroll
    for (int mk = 1; mk < 16; mk <<= 1) {
      s[i] += __shfl_xor(s[i], mk, 64);
      vm[i] = fmaxf(vm[i], __shfl_xor(vm[i], mk, 64));
      vt[i] = fmaxf(vt[i], __shfl_xor(vt[i], mk, 64));
    }
    if (lr == 0) {
      int row = r0 + (i >> 2) * 16 + lg * 4 + (i & 3);
      int idx = row * PARTS + part;
      sp[idx] = s[i]; vmp[idx] = vm[i]; vtp[idx] = vt[i];
    }
  }
}

// ---- kernel 4: combine partials per row, margin math, reduce loss/acc ----
__global__ void k_combine(const float* __restrict__ sp, const float* __restrict__ vmp,
                          const float* __restrict__ vtp, float* __restrict__ accum) {
  int t = threadIdx.x;
  int row = blockIdx.x * 256 + t;
  float4 s4a[4], m4a[4], t4a[4];
#pragma unroll
  for (int q = 0; q < 4; ++q) {
    s4a[q] = reinterpret_cast<const float4*>(sp + row * PARTS)[q];
    m4a[q] = reinterpret_cast<const float4*>(vmp + row * PARTS)[q];
    t4a[q] = reinterpret_cast<const float4*>(vtp + row * PARTS)[q];
  }
  float s = 0.f, vm = -2.f, vt = -2.f;
#pragma unroll
  for (int q = 0; q < 4; ++q) {
    s += s4a[q].x + s4a[q].y + s4a[q].z + s4a[q].w;
    vm = fmaxf(vm, fmaxf(fmaxf(m4a[q].x, m4a[q].y), fmaxf(m4a[q].z, m4a[q].w)));
    vt = fmaxf(vt, fmaxf(fmaxf(t4a[q].x, t4a[q].y), fmaxf(t4a[q].z, t4a[q].w)));
  }
  float vtc = fminf(fmaxf(vt, -1.f + 1e-7f), 1.f + 1e-7f);
  float sn = sqrtf(fmaxf(1.f - vtc * vtc, 0.f));
  float tg = 30.f * (vtc * COSM - sn * SINM);
  float sadj = s - __expf(30.f * vt - 30.f) + __expf(tg - 30.f);
  float loss = 30.f + logf(sadj) - tg;
  float corr = (tg >= 30.f * vm) ? 1.f : 0.f;
#pragma unroll
  for (int mk = 32; mk >= 1; mk >>= 1) {
    loss += __shfl_xor(loss, mk, 64);
    corr += __shfl_xor(corr, mk, 64);
  }
  __shared__ float ls[4], cs[4];
  if ((t & 63) == 0) { ls[t >> 6] = loss; cs[t >> 6] = corr; }
  __syncthreads();
  if (t == 0) {
    atomicAdd(accum + 0, ls[0] + ls[1] + ls[2] + ls[3]);
    atomicAdd(accum + 1, cs[0] + cs[1] + cs[2] + cs[3]);
  }
}

// ---- kernel 5: finalize ----
__global__ void k_final(const float* __restrict__ accum, float* __restrict__ out) {
  out[0] = accum[0] / (float)BB;
  out[1] = accum[1] * (100.0f / (float)BB);
}

extern "C" void kernel_launch(void* const* d_in, const int* in_sizes, int n_in,
                              void* d_out, int out_size, void* d_ws, size_t ws_size,
                              hipStream_t stream) {
  const float* x = (const float*)d_in[0];
  const float* W = (const float*)d_in[1];
  const int* label = (const int*)d_in[2];
  float* out = (float*)d_out;

  char* ws = (char*)d_ws;
  unsigned short* wnS = (unsigned short*)(ws);               // 6144*256*2 = 3,145,728
  unsigned short* xnS = (unsigned short*)(ws + 3145728);     // 4096*256*2 = 2,097,152
  size_t po = 5242880;
  float* sp  = (float*)(ws + po);                            // 4096*16*4 = 262,144
  float* vmp = (float*)(ws + po + 262144);
  float* vtp = (float*)(ws + po + 524288);
  float* accum = (float*)(ws + po + 786432);

  hipMemsetAsync(accum, 0, 8, stream);
  k_xnorm<<<BB / 4, 256, 0, stream>>>(x, xnS);
  k_wnorm<<<NCHUNK, 256, 0, stream>>>(W, wnS);
  k_main<<<512, 256, 0, stream>>>(xnS, wnS, label, sp, vmp, vtp);
  k_combine<<<BB / 256, 256, 0, stream>>>(sp, vmp, vtp, accum);
  k_final<<<1, 1, 0, stream>>>(accum, out);
}